// Round 1
// baseline (266.807 us; speedup 1.0000x reference)
//
#include <hip/hip_runtime.h>
#include <hip/hip_bf16.h>

// EdgeDetourHead: B=2, N=512, E=128, H=256
// R7: hoist the hj@W1b term out of the pair loop entirely.
//   PA[b,i,:] = h_i@W1a + b1   (fp32, prep)          -- as before
//   PB[b,j,:] = h_j@W1b        (fp32, prep)          -- NEW
//   layer1 per pair tile: C1^T = W1c^T @ |h_i-h_j|^T (K=128 only, was K=256+rank1)
//   epi1: h1 = relu(C1^T + PA[i][f] + PB[j][f] + e_ij*w1d[f])   (all fp32 adds)
// Removes: ldsHJ build (half of phase-1), 64 hj-MFMAs/wave, 8 rank-1 MFMAs/wave,
// w1b/w1d frag packing + loads. MFMA/wave: 264 -> 192.

#define BN 512
#define EE 128
#define HH 256

typedef __attribute__((ext_vector_type(8)))  short short8;
typedef __attribute__((ext_vector_type(4)))  short short4v;
typedef __attribute__((ext_vector_type(16))) float f32x16;
typedef __attribute__((ext_vector_type(4)))  float f32x4;

static __device__ __forceinline__ unsigned short f2bf(float f) {
    __bf16 h = (__bf16)f;
    return __builtin_bit_cast(unsigned short, h);
}
static __device__ __forceinline__ f32x16 zero16() {
    f32x16 v;
    #pragma unroll
    for (int i = 0; i < 16; ++i) v[i] = 0.f;
    return v;
}
#define MFMA(a, b, c) __builtin_amdgcn_mfma_f32_32x32x16_bf16((a), (b), (c), 0, 0, 0)

// ---------------- kernel 0: prep ----------------
// blocks 0..255: weight pack. Packed frag idx = ((kb*8 + mtile)*64 + l)*8 + t ;
//   value W[kb*16+(l>>5)*8+t][mtile*32+(l&31)]  == A-frag of W^T.
// blocks 256..1279: PA = h_i@W1a + b1 and PB = h_j@W1b (fp32).
__global__ void prep(const float* __restrict__ node, const float* __restrict__ W1,
                     const float* __restrict__ W2, const float* __restrict__ b1,
                     float* __restrict__ PA, float* __restrict__ PB,
                     unsigned short* __restrict__ w1c_p, unsigned short* __restrict__ w2_p) {
    int blk = blockIdx.x;
    if (blk < 256) {
        int idx = blk * 256 + threadIdx.x;             // 0..65535
        int t = idx & 7, l = (idx >> 3) & 63, mt = (idx >> 9) & 7, kb = idx >> 12;
        int k = kb * 16 + (l >> 5) * 8 + t, m = mt * 32 + (l & 31);
        w2_p[idx] = f2bf(W2[k * HH + m]);              // W2^T A-frags: kb 0..15
        if (idx < 32768)                               // W1c^T: kb 0..7
            w1c_p[idx] = f2bf(W1[(2 * EE + k) * HH + m]);
    } else {
        int bi = blk - 256;                            // 0..1023 = b*BN + n
        int h = threadIdx.x;
        const float* nd = node + (size_t)bi * EE;
        float sa = b1[h], sb = 0.f;
        #pragma unroll 8
        for (int e = 0; e < EE; ++e) {
            float nv = nd[e];
            sa += nv * W1[e * HH + h];
            sb += nv * W1[(EE + e) * HH + h];
        }
        PA[bi * HH + h] = sa;
        PB[bi * HH + h] = sb;
    }
}

// ---------------- kernel 1: fused main, transposed (one 128-pair tile per WG) --------
// Wave w owns feature m-tiles {2w, 2w+1} (64 feats) x all 4 pair n-tiles.
__global__ __launch_bounds__(256, 2) void edge_main(
    const float* __restrict__ node, const float* __restrict__ euclid,
    const float* __restrict__ W1, const float* __restrict__ W3,
    const float* __restrict__ b3, const float* __restrict__ b2v,
    const float* __restrict__ PA, const float* __restrict__ PB,
    const unsigned short* __restrict__ w1c_p, const unsigned short* __restrict__ w2_p,
    float* __restrict__ out)
{
    // Phase 1/K1: D [128][136] (34816 B) lives in the low half of the buffer;
    // after K1 the whole buffer becomes h1 [128][264] (67584 B).
    __shared__ __align__(16) unsigned short lds_buf[128 * 264];
    __shared__ float pp[512];

    const int jt = blockIdx.x, i = blockIdx.y, b = blockIdx.z;
    const int jbase = jt * 128;
    const int tid = threadIdx.x, wave = tid >> 6, lane = tid & 63;
    const int m0 = lane & 31, q = lane >> 5;

    unsigned short* ldsD  = lds_buf;                   // [128][136]
    unsigned short* ldsH1 = lds_buf;                   // [128][264], overlays D after K1

    // ---- phase 1: build D=|h_i-h_j| (bf16) row-major [pair][e], stride 136 ----
    {
        int row = tid >> 1, half = tid & 1;
        const f32x4* nj = (const f32x4*)(node + ((size_t)b * BN + jbase + row) * EE);
        const f32x4* hv = (const f32x4*)(node + ((size_t)b * BN + i) * EE);
        #pragma unroll
        for (int g = 0; g < 8; ++g) {
            int c0 = half * 16 + g * 2;                // f32x4 index
            f32x4 a0 = nj[c0], a1 = nj[c0 + 1];
            f32x4 h0 = hv[c0], h1v = hv[c0 + 1];
            short8 pd;
            #pragma unroll
            for (int u = 0; u < 4; ++u) {
                pd[u]     = (short)f2bf(fabsf(a0[u] - h0[u]));
                pd[4 + u] = (short)f2bf(fabsf(a1[u] - h1v[u]));
            }
            *(short8*)&ldsD[row * 136 + half * 64 + g * 8] = pd;
        }
    }
    __syncthreads();

    // ---- layer 1 (transposed): C1^T = W1c^T @ D^T, K=128 ----
    f32x16 acc[2][4];
    #pragma unroll
    for (int mt = 0; mt < 2; ++mt)
        #pragma unroll
        for (int nt = 0; nt < 4; ++nt) acc[mt][nt] = zero16();
    {
        const short8* wc = (const short8*)w1c_p;
        const int mtg = wave * 2;
        #pragma unroll
        for (int kb = 0; kb < 8; ++kb) {
            short8 ac0 = wc[(kb * 8 + mtg + 0) * 64 + lane];
            short8 ac1 = wc[(kb * 8 + mtg + 1) * 64 + lane];
            #pragma unroll
            for (int nt = 0; nt < 4; ++nt) {
                short8 bD = *(const short8*)&ldsD[(nt * 32 + m0) * 136 + kb * 16 + q * 8];
                acc[0][nt] = MFMA(ac0, bD, acc[0][nt]);
                acc[1][nt] = MFMA(ac1, bD, acc[1][nt]);
            }
        }
    }
    __syncthreads();   // D dead; buffer becomes h1

    // ---- epi1: h1[pair][f] = relu(C1^T + PA[i][f] + PB[j][f] + e_ij*w1d[f]) ----
    {
        const float* paB  = PA + ((size_t)b * BN + i) * HH;
        const float* pbB  = PB + ((size_t)b * BN + jbase) * HH;
        const float* wd   = W1 + (size_t)(3 * EE) * HH;          // w1d row (384)
        const float* erow = euclid + ((size_t)b * BN + i) * BN + jbase;
        float ev[4];
        #pragma unroll
        for (int nt = 0; nt < 4; ++nt) ev[nt] = erow[nt * 32 + m0];
        #pragma unroll
        for (int mt = 0; mt < 2; ++mt) {
            #pragma unroll
            for (int rg = 0; rg < 4; ++rg) {
                int f0 = wave * 64 + mt * 32 + rg * 8;           // wave-uniform
                f32x4 plo = *(const f32x4*)&paB[f0];
                f32x4 phi = *(const f32x4*)&paB[f0 + 4];
                f32x4 dlo = *(const f32x4*)&wd[f0];
                f32x4 dhi = *(const f32x4*)&wd[f0 + 4];
                f32x4 pav, wdv;
                #pragma unroll
                for (int u = 0; u < 4; ++u) {
                    pav[u] = q ? phi[u] : plo[u];
                    wdv[u] = q ? dhi[u] : dlo[u];
                }
                #pragma unroll
                for (int nt = 0; nt < 4; ++nt) {
                    f32x4 pbv = *(const f32x4*)&pbB[(size_t)(nt * 32 + m0) * HH + f0 + 4 * q];
                    short4v w;
                    #pragma unroll
                    for (int u = 0; u < 4; ++u) {
                        float v = acc[mt][nt][rg * 4 + u] + pav[u] + pbv[u] + ev[nt] * wdv[u];
                        v = v > 0.f ? v : 0.f;
                        w[u] = (short)f2bf(v);
                    }
                    *(short4v*)&ldsH1[(nt * 32 + m0) * 264 + f0 + 4 * q] = w;
                }
            }
        }
    }
    __syncthreads();

    // ---- layer 2 (transposed): C2^T = W2^T @ h1^T, K=256 ----
    f32x16 c2[2][4];
    #pragma unroll
    for (int mt = 0; mt < 2; ++mt)
        #pragma unroll
        for (int nt = 0; nt < 4; ++nt) c2[mt][nt] = zero16();
    {
        const short8* w2f = (const short8*)w2_p;
        const int mtg = wave * 2;
        #pragma unroll
        for (int kb = 0; kb < 16; ++kb) {
            short8 a0 = w2f[(kb * 8 + mtg + 0) * 64 + lane];
            short8 a1 = w2f[(kb * 8 + mtg + 1) * 64 + lane];
            #pragma unroll
            for (int nt = 0; nt < 4; ++nt) {
                short8 bh = *(const short8*)&ldsH1[(nt * 32 + m0) * 264 + kb * 16 + q * 8];
                c2[0][nt] = MFMA(a0, bh, c2[0][nt]);
                c2[1][nt] = MFMA(a1, bh, c2[1][nt]);
            }
        }
    }

    // ---- layer 3 in registers: s[nt] = sum_feat relu(c2+b2[feat]) * W3[feat] ----
    {
        float s[4] = {0.f, 0.f, 0.f, 0.f};
        #pragma unroll
        for (int mt = 0; mt < 2; ++mt) {
            #pragma unroll
            for (int rg = 0; rg < 4; ++rg) {
                int f0 = wave * 64 + mt * 32 + rg * 8;           // wave-uniform
                f32x4 blo = *(const f32x4*)&b2v[f0];
                f32x4 bhi = *(const f32x4*)&b2v[f0 + 4];
                f32x4 wlo = *(const f32x4*)&W3[f0];
                f32x4 whi = *(const f32x4*)&W3[f0 + 4];
                #pragma unroll
                for (int u = 0; u < 4; ++u) {
                    float bb = q ? bhi[u] : blo[u];
                    float ww = q ? whi[u] : wlo[u];
                    #pragma unroll
                    for (int nt = 0; nt < 4; ++nt) {
                        float h2 = c2[mt][nt][rg * 4 + u] + bb;
                        h2 = h2 > 0.f ? h2 : 0.f;
                        s[nt] += h2 * ww;
                    }
                }
            }
        }
        #pragma unroll
        for (int nt = 0; nt < 4; ++nt)
            s[nt] += __shfl_xor(s[nt], 32, 64);       // fold q-halves
        if (lane < 32) {
            #pragma unroll
            for (int nt = 0; nt < 4; ++nt)
                pp[wave * 128 + nt * 32 + lane] = s[nt];
        }
    }
    __syncthreads();
    if (tid < 128) {
        float v = pp[tid] + pp[128 + tid] + pp[256 + tid] + pp[384 + tid] + b3[0];
        out[((size_t)b * BN + i) * BN + jbase + tid] = v;
    }
}

// ---------------- kernel 2: in-place symmetrize + zero diagonal ----------------
__global__ void symmetrize(float* __restrict__ out) {
    int b = blockIdx.z, ti = blockIdx.y, tj = blockIdx.x;
    if (tj < ti) return;
    int i = ti * 32 + threadIdx.y, j = tj * 32 + threadIdx.x;
    float* p = out + (size_t)b * BN * BN;
    if (i == j) { p[(size_t)i * BN + j] = 0.f; return; }
    if (j < i) return;
    float a = p[(size_t)i * BN + j];
    float c = p[(size_t)j * BN + i];
    float v = 0.5f * (a + c);
    p[(size_t)i * BN + j] = v;
    p[(size_t)j * BN + i] = v;
}

extern "C" void kernel_launch(void* const* d_in, const int* in_sizes, int n_in,
                              void* d_out, int out_size, void* d_ws, size_t ws_size,
                              hipStream_t stream) {
    const float* node   = (const float*)d_in[0];
    const float* euclid = (const float*)d_in[2];
    const float* W1     = (const float*)d_in[3];
    const float* b1     = (const float*)d_in[4];
    const float* W2     = (const float*)d_in[5];
    const float* b2     = (const float*)d_in[6];
    const float* W3     = (const float*)d_in[7];
    const float* b3     = (const float*)d_in[8];
    float* out = (float*)d_out;

    char* ws = (char*)d_ws;
    float*          PA    = (float*)ws;                                   // 1 MB
    float*          PB    = (float*)(ws + (1u << 20));                    // 1 MB
    unsigned short* w1c_p = (unsigned short*)(ws + (2u << 20));           // 64 KB
    unsigned short* w2_p  = (unsigned short*)(ws + (2u << 20) + 65536);   // 128 KB

    prep<<<1280, 256, 0, stream>>>(node, W1, W2, b1, PA, PB, w1c_p, w2_p);
    edge_main<<<dim3(BN / 128, BN, 2), 256, 0, stream>>>(
        node, euclid, W1, W3, b3, b2, PA, PB, w1c_p, w2_p, out);
    symmetrize<<<dim3(BN / 32, BN / 32, 2), dim3(32, 32), 0, stream>>>(out);
}

// Round 2
// 242.174 us; speedup vs baseline: 1.1017x; 1.1017x over previous
//
#include <hip/hip_runtime.h>
#include <hip/hip_bf16.h>

// EdgeDetourHead: B=2, N=512, E=128, H=256
// R8: keep R7's algebraic hoist (PB[j,f]=h_j@W1b precomputed; 192 MFMA/wave),
// fix R7's regression: the epi1 PB read was a 1KB-strided per-lane gather
// (32 uncoalesced lines/wave-inst, latency-bound between barriers).
//  - PB stored TRANSPOSED + 4-feat-interleaved: PBT[b][f>>2][j][f&3] so epi1
//    reads one aligned f32x4 per (mt,rg,nt) with lanes (m0) coalesced.
//  - mt=0 half of the PB tile (64 VGPRs) prefetched BEFORE the layer-1 MFMA
//    loop; latency hides under phase-1 + 64 MFMAs, drained by the barrier.

#define BN 512
#define EE 128
#define HH 256

typedef __attribute__((ext_vector_type(8)))  short short8;
typedef __attribute__((ext_vector_type(4)))  short short4v;
typedef __attribute__((ext_vector_type(16))) float f32x16;
typedef __attribute__((ext_vector_type(4)))  float f32x4;

static __device__ __forceinline__ unsigned short f2bf(float f) {
    __bf16 h = (__bf16)f;
    return __builtin_bit_cast(unsigned short, h);
}
static __device__ __forceinline__ f32x16 zero16() {
    f32x16 v;
    #pragma unroll
    for (int i = 0; i < 16; ++i) v[i] = 0.f;
    return v;
}
#define MFMA(a, b, c) __builtin_amdgcn_mfma_f32_32x32x16_bf16((a), (b), (c), 0, 0, 0)

// ---------------- kernel 0: prep ----------------
// blocks 0..255: weight pack. Packed frag idx = ((kb*8 + mtile)*64 + l)*8 + t ;
//   value W[kb*16+(l>>5)*8+t][mtile*32+(l&31)]  == A-frag of W^T.
// blocks 256..1279: PA[b,i,f] = h_i@W1a + b1 (fp32, row-major) and
//                   PBT[b][f>>2][j][f&3] = (h_j@W1b)[f] (fp32, transposed).
__global__ void prep(const float* __restrict__ node, const float* __restrict__ W1,
                     const float* __restrict__ W2, const float* __restrict__ b1,
                     float* __restrict__ PA, float* __restrict__ PBT,
                     unsigned short* __restrict__ w1c_p, unsigned short* __restrict__ w2_p) {
    int blk = blockIdx.x;
    if (blk < 256) {
        int idx = blk * 256 + threadIdx.x;             // 0..65535
        int t = idx & 7, l = (idx >> 3) & 63, mt = (idx >> 9) & 7, kb = idx >> 12;
        int k = kb * 16 + (l >> 5) * 8 + t, m = mt * 32 + (l & 31);
        w2_p[idx] = f2bf(W2[k * HH + m]);              // W2^T A-frags: kb 0..15
        if (idx < 32768)                               // W1c^T: kb 0..7
            w1c_p[idx] = f2bf(W1[(2 * EE + k) * HH + m]);
    } else {
        int bi = blk - 256;                            // 0..1023 = b*BN + n
        int h = threadIdx.x;
        const float* nd = node + (size_t)bi * EE;
        float sa = b1[h], sb = 0.f;
        #pragma unroll 8
        for (int e = 0; e < EE; ++e) {
            float nv = nd[e];
            sa += nv * W1[e * HH + h];
            sb += nv * W1[(EE + e) * HH + h];
        }
        PA[bi * HH + h] = sa;
        PBT[(((size_t)(bi >> 9) * 64 + (h >> 2)) * BN + (bi & 511)) * 4 + (h & 3)] = sb;
    }
}

// ---------------- kernel 1: fused main, transposed (one 128-pair tile per WG) --------
// Wave w owns feature m-tiles {2w, 2w+1} (64 feats) x all 4 pair n-tiles.
__global__ __launch_bounds__(256, 2) void edge_main(
    const float* __restrict__ node, const float* __restrict__ euclid,
    const float* __restrict__ W1, const float* __restrict__ W3,
    const float* __restrict__ b3, const float* __restrict__ b2v,
    const float* __restrict__ PA, const float* __restrict__ PBT,
    const unsigned short* __restrict__ w1c_p, const unsigned short* __restrict__ w2_p,
    float* __restrict__ out)
{
    // Phase 1/K1: D [128][136] (34816 B) lives in the low half of the buffer;
    // after K1 the whole buffer becomes h1 [128][264] (67584 B).
    __shared__ __align__(16) unsigned short lds_buf[128 * 264];
    __shared__ float pp[512];

    const int jt = blockIdx.x, i = blockIdx.y, b = blockIdx.z;
    const int jbase = jt * 128;
    const int tid = threadIdx.x, wave = tid >> 6, lane = tid & 63;
    const int m0 = lane & 31, q = lane >> 5;

    unsigned short* ldsD  = lds_buf;                   // [128][136]
    unsigned short* ldsH1 = lds_buf;                   // [128][264], overlays D after K1

    // ---- prefetch (independent of LDS): mt=0 PB tile + euclid row ----
    const float* pbt = PBT + (size_t)b * 64 * BN * 4;
    f32x4 pb0[4][4];                                   // [rg][nt], feats mt=0
    #pragma unroll
    for (int rg = 0; rg < 4; ++rg) {
        int f0 = wave * 64 + rg * 8;                   // wave-uniform
        #pragma unroll
        for (int nt = 0; nt < 4; ++nt)
            pb0[rg][nt] = *(const f32x4*)&pbt[
                (((size_t)(f0 >> 2) + q) * BN + jbase + nt * 32 + m0) * 4];
    }
    const float* erow = euclid + ((size_t)b * BN + i) * BN + jbase;
    float ev[4];
    #pragma unroll
    for (int nt = 0; nt < 4; ++nt) ev[nt] = erow[nt * 32 + m0];

    // ---- phase 1: build D=|h_i-h_j| (bf16) row-major [pair][e], stride 136 ----
    {
        int row = tid >> 1, half = tid & 1;
        const f32x4* nj = (const f32x4*)(node + ((size_t)b * BN + jbase + row) * EE);
        const f32x4* hv = (const f32x4*)(node + ((size_t)b * BN + i) * EE);
        #pragma unroll
        for (int g = 0; g < 8; ++g) {
            int c0 = half * 16 + g * 2;                // f32x4 index
            f32x4 a0 = nj[c0], a1 = nj[c0 + 1];
            f32x4 h0 = hv[c0], h1v = hv[c0 + 1];
            short8 pd;
            #pragma unroll
            for (int u = 0; u < 4; ++u) {
                pd[u]     = (short)f2bf(fabsf(a0[u] - h0[u]));
                pd[4 + u] = (short)f2bf(fabsf(a1[u] - h1v[u]));
            }
            *(short8*)&ldsD[row * 136 + half * 64 + g * 8] = pd;
        }
    }
    __syncthreads();

    // ---- layer 1 (transposed): C1^T = W1c^T @ D^T, K=128 ----
    f32x16 acc[2][4];
    #pragma unroll
    for (int mt = 0; mt < 2; ++mt)
        #pragma unroll
        for (int nt = 0; nt < 4; ++nt) acc[mt][nt] = zero16();
    {
        const short8* wc = (const short8*)w1c_p;
        const int mtg = wave * 2;
        #pragma unroll
        for (int kb = 0; kb < 8; ++kb) {
            short8 ac0 = wc[(kb * 8 + mtg + 0) * 64 + lane];
            short8 ac1 = wc[(kb * 8 + mtg + 1) * 64 + lane];
            #pragma unroll
            for (int nt = 0; nt < 4; ++nt) {
                short8 bD = *(const short8*)&ldsD[(nt * 32 + m0) * 136 + kb * 16 + q * 8];
                acc[0][nt] = MFMA(ac0, bD, acc[0][nt]);
                acc[1][nt] = MFMA(ac1, bD, acc[1][nt]);
            }
        }
    }
    __syncthreads();   // D dead; buffer becomes h1

    // ---- epi1: h1[pair][f] = relu(C1^T + PA[i][f] + PB[j][f] + e_ij*w1d[f]) ----
    {
        const float* paB = PA + ((size_t)b * BN + i) * HH;
        const float* wd  = W1 + (size_t)(3 * EE) * HH;           // w1d row (384)
        #pragma unroll
        for (int mt = 0; mt < 2; ++mt) {
            #pragma unroll
            for (int rg = 0; rg < 4; ++rg) {
                int f0 = wave * 64 + mt * 32 + rg * 8;           // wave-uniform
                f32x4 plo = *(const f32x4*)&paB[f0];
                f32x4 phi = *(const f32x4*)&paB[f0 + 4];
                f32x4 dlo = *(const f32x4*)&wd[f0];
                f32x4 dhi = *(const f32x4*)&wd[f0 + 4];
                f32x4 pav, wdv;
                #pragma unroll
                for (int u = 0; u < 4; ++u) {
                    pav[u] = q ? phi[u] : plo[u];
                    wdv[u] = q ? dhi[u] : dlo[u];
                }
                #pragma unroll
                for (int nt = 0; nt < 4; ++nt) {
                    f32x4 pbv = (mt == 0) ? pb0[rg][nt]
                        : *(const f32x4*)&pbt[
                            (((size_t)(f0 >> 2) + q) * BN + jbase + nt * 32 + m0) * 4];
                    short4v w;
                    #pragma unroll
                    for (int u = 0; u < 4; ++u) {
                        float v = acc[mt][nt][rg * 4 + u] + pav[u] + pbv[u] + ev[nt] * wdv[u];
                        v = v > 0.f ? v : 0.f;
                        w[u] = (short)f2bf(v);
                    }
                    *(short4v*)&ldsH1[(nt * 32 + m0) * 264 + f0 + 4 * q] = w;
                }
            }
        }
    }
    __syncthreads();

    // ---- layer 2 (transposed): C2^T = W2^T @ h1^T, K=256 ----
    f32x16 c2[2][4];
    #pragma unroll
    for (int mt = 0; mt < 2; ++mt)
        #pragma unroll
        for (int nt = 0; nt < 4; ++nt) c2[mt][nt] = zero16();
    {
        const short8* w2f = (const short8*)w2_p;
        const int mtg = wave * 2;
        #pragma unroll
        for (int kb = 0; kb < 16; ++kb) {
            short8 a0 = w2f[(kb * 8 + mtg + 0) * 64 + lane];
            short8 a1 = w2f[(kb * 8 + mtg + 1) * 64 + lane];
            #pragma unroll
            for (int nt = 0; nt < 4; ++nt) {
                short8 bh = *(const short8*)&ldsH1[(nt * 32 + m0) * 264 + kb * 16 + q * 8];
                c2[0][nt] = MFMA(a0, bh, c2[0][nt]);
                c2[1][nt] = MFMA(a1, bh, c2[1][nt]);
            }
        }
    }

    // ---- layer 3 in registers: s[nt] = sum_feat relu(c2+b2[feat]) * W3[feat] ----
    {
        float s[4] = {0.f, 0.f, 0.f, 0.f};
        #pragma unroll
        for (int mt = 0; mt < 2; ++mt) {
            #pragma unroll
            for (int rg = 0; rg < 4; ++rg) {
                int f0 = wave * 64 + mt * 32 + rg * 8;           // wave-uniform
                f32x4 blo = *(const f32x4*)&b2v[f0];
                f32x4 bhi = *(const f32x4*)&b2v[f0 + 4];
                f32x4 wlo = *(const f32x4*)&W3[f0];
                f32x4 whi = *(const f32x4*)&W3[f0 + 4];
                #pragma unroll
                for (int u = 0; u < 4; ++u) {
                    float bb = q ? bhi[u] : blo[u];
                    float ww = q ? whi[u] : wlo[u];
                    #pragma unroll
                    for (int nt = 0; nt < 4; ++nt) {
                        float h2 = c2[mt][nt][rg * 4 + u] + bb;
                        h2 = h2 > 0.f ? h2 : 0.f;
                        s[nt] += h2 * ww;
                    }
                }
            }
        }
        #pragma unroll
        for (int nt = 0; nt < 4; ++nt)
            s[nt] += __shfl_xor(s[nt], 32, 64);       // fold q-halves
        if (lane < 32) {
            #pragma unroll
            for (int nt = 0; nt < 4; ++nt)
                pp[wave * 128 + nt * 32 + lane] = s[nt];
        }
    }
    __syncthreads();
    if (tid < 128) {
        float v = pp[tid] + pp[128 + tid] + pp[256 + tid] + pp[384 + tid] + b3[0];
        out[((size_t)b * BN + i) * BN + jbase + tid] = v;
    }
}

// ---------------- kernel 2: in-place symmetrize + zero diagonal ----------------
__global__ void symmetrize(float* __restrict__ out) {
    int b = blockIdx.z, ti = blockIdx.y, tj = blockIdx.x;
    if (tj < ti) return;
    int i = ti * 32 + threadIdx.y, j = tj * 32 + threadIdx.x;
    float* p = out + (size_t)b * BN * BN;
    if (i == j) { p[(size_t)i * BN + j] = 0.f; return; }
    if (j < i) return;
    float a = p[(size_t)i * BN + j];
    float c = p[(size_t)j * BN + i];
    float v = 0.5f * (a + c);
    p[(size_t)i * BN + j] = v;
    p[(size_t)j * BN + i] = v;
}

extern "C" void kernel_launch(void* const* d_in, const int* in_sizes, int n_in,
                              void* d_out, int out_size, void* d_ws, size_t ws_size,
                              hipStream_t stream) {
    const float* node   = (const float*)d_in[0];
    const float* euclid = (const float*)d_in[2];
    const float* W1     = (const float*)d_in[3];
    const float* b1     = (const float*)d_in[4];
    const float* W2     = (const float*)d_in[5];
    const float* b2     = (const float*)d_in[6];
    const float* W3     = (const float*)d_in[7];
    const float* b3     = (const float*)d_in[8];
    float* out = (float*)d_out;

    char* ws = (char*)d_ws;
    float*          PA    = (float*)ws;                                   // 1 MB
    float*          PBT   = (float*)(ws + (1u << 20));                    // 1 MB
    unsigned short* w1c_p = (unsigned short*)(ws + (2u << 20));           // 64 KB
    unsigned short* w2_p  = (unsigned short*)(ws + (2u << 20) + 65536);   // 128 KB

    prep<<<1280, 256, 0, stream>>>(node, W1, W2, b1, PA, PBT, w1c_p, w2_p);
    edge_main<<<dim3(BN / 128, BN, 2), 256, 0, stream>>>(
        node, euclid, W1, W3, b3, b2, PA, PBT, w1c_p, w2_p, out);
    symmetrize<<<dim3(BN / 32, BN / 32, 2), dim3(32, 32), 0, stream>>>(out);
}